// Round 1
// baseline (108.173 us; speedup 1.0000x reference)
//
#include <hip/hip_runtime.h>
#include <hip/hip_bf16.h>

// GATLayer reduces to out = x @ W^T:
//   out = einsum('bnjh,bnhd->bnhd', alpha, h) with j only in alpha
//   => out = h * sum_j(alpha) = h * 1 = h = x @ W^T
// adj and a_w are numerically dead. B=4, N=2048, IN=256, OUT=256.

typedef __attribute__((ext_vector_type(8))) short short8;
typedef __attribute__((ext_vector_type(4))) float floatx4;

__device__ inline short f2bf(float f) {
    // round-to-nearest-even bf16 (inputs are finite/normal-ish; NaN not expected)
    unsigned u = __float_as_uint(f);
    unsigned r = u + 0x7fffu + ((u >> 16) & 1u);
    return (short)(r >> 16);
}

__global__ void cast_w_kernel(const float* __restrict__ W, short* __restrict__ Wb) {
    int idx = blockIdx.x * blockDim.x + threadIdx.x;   // 16384 threads, 1 float4 each
    float4 v = ((const float4*)W)[idx];
    short4 s;
    s.x = f2bf(v.x); s.y = f2bf(v.y); s.z = f2bf(v.z); s.w = f2bf(v.w);
    ((short4*)Wb)[idx] = s;
}

// 16 rows per block, 4 waves, wave w covers output cols [w*64, w*64+64).
// K = 256 in 8 chunks of 32 via mfma_f32_16x16x32_bf16.
#define LDS_STRIDE 264   // 256 + 8 shorts pad: keeps 16B alignment, breaks bank aliasing to 2-way (free)

__global__ __launch_bounds__(256) void gemm_xwt(const float* __restrict__ X,
                                                const short* __restrict__ Wb,
                                                float* __restrict__ out) {
    __shared__ short xlds[16 * LDS_STRIDE];

    const int r0 = blockIdx.x * 16;          // global row base (b*N + n flattened)
    const int t  = threadIdx.x;

    // Stage x tile (16 rows x 256 f) fp32 -> bf16 in LDS. 1024 float4 loads, 4 per thread.
    const float4* X4 = (const float4*)(X + (size_t)r0 * 256);
    #pragma unroll
    for (int k = 0; k < 4; ++k) {
        int idx = t + 256 * k;               // 0..1023
        int row = idx >> 6;                  // /64 float4 per row
        int c4  = idx & 63;
        float4 v = X4[idx];
        short4 s;
        s.x = f2bf(v.x); s.y = f2bf(v.y); s.z = f2bf(v.z); s.w = f2bf(v.w);
        *(short4*)&xlds[row * LDS_STRIDE + c4 * 4] = s;
    }
    __syncthreads();

    const int lane = t & 63;
    const int wave = t >> 6;
    const int q    = lane >> 4;              // k-group (0..3)
    const int m    = lane & 15;              // A-row / B-col / C-col
    const int o0   = wave * 64;

    floatx4 acc[4] = {};

    #pragma unroll
    for (int it = 0; it < 8; ++it) {
        const int f0 = it * 32;
        // A fragment: A[m][k], k = q*8 + e  (8 contiguous bf16, 16B aligned)
        short8 a = *(const short8*)&xlds[m * LDS_STRIDE + f0 + q * 8];
        #pragma unroll
        for (int nt = 0; nt < 4; ++nt) {
            // B fragment: B[k][n] = W[o0+nt*16+n][f0+k] -> contiguous in f
            const short8 b = *(const short8*)&Wb[(size_t)(o0 + nt * 16 + m) * 256 + f0 + q * 8];
            acc[nt] = __builtin_amdgcn_mfma_f32_16x16x32_bf16(a, b, acc[nt], 0, 0, 0);
        }
    }

    // C/D layout: col = lane&15, row = (lane>>4)*4 + reg
    #pragma unroll
    for (int nt = 0; nt < 4; ++nt) {
        #pragma unroll
        for (int reg = 0; reg < 4; ++reg) {
            int row = q * 4 + reg;
            int col = o0 + nt * 16 + m;
            out[(size_t)(r0 + row) * 256 + col] = acc[nt][reg];
        }
    }
}

extern "C" void kernel_launch(void* const* d_in, const int* in_sizes, int n_in,
                              void* d_out, int out_size, void* d_ws, size_t ws_size,
                              hipStream_t stream) {
    const float* x  = (const float*)d_in[0];   // [4][2048][256] fp32
    // d_in[1] = adj  (dead), d_in[3] = a_w (dead)
    const float* W  = (const float*)d_in[2];   // [256][256] fp32
    float* out      = (float*)d_out;           // [4][2048][256] fp32

    short* Wb = (short*)d_ws;                  // 256*256 bf16 = 128 KB scratch

    cast_w_kernel<<<64, 256, 0, stream>>>(W, Wb);
    gemm_xwt<<<512, 256, 0, stream>>>(x, Wb, out);
}

// Round 2
// 106.855 us; speedup vs baseline: 1.0123x; 1.0123x over previous
//
#include <hip/hip_runtime.h>
#include <hip/hip_bf16.h>

// GATLayer reduces to out = x @ W^T:
//   out = einsum('bnjh,bnhd->bnhd', alpha, h); j appears only in alpha,
//   and softmax over j sums to 1 => out = h = x @ W^T.
// adj and a_w are numerically dead. B=4, N=2048, IN=256, OUT=256.
//
// Single fused kernel: 256 blocks (1/CU) x 256 threads, 32 rows/block.
// x staged fp32->bf16 in LDS; W loaded fp32 from global (L2-resident,
// 256KB) and cast in-register; each B fragment feeds 2 row-tile MFMAs.

typedef __attribute__((ext_vector_type(8))) short short8;
typedef __attribute__((ext_vector_type(4))) float floatx4;

__device__ inline short f2bf(float f) {
    // round-to-nearest-even bf16
    unsigned u = __float_as_uint(f);
    unsigned r = u + 0x7fffu + ((u >> 16) & 1u);
    return (short)(r >> 16);
}

#define LSTR 264  // 256 + 8 shorts: 16B-aligned rows, worst bank aliasing 2-way (free)

__global__ __launch_bounds__(256) void gat_gemm(const float* __restrict__ X,
                                                const float* __restrict__ W,
                                                float* __restrict__ out) {
    __shared__ short xlds[32 * LSTR];

    const int r0 = blockIdx.x * 32;   // global row base (b*N + n flattened)
    const int t  = threadIdx.x;

    // Stage 32 rows x 256 f (fp32 -> bf16). 2048 float4 loads, 8 per thread, coalesced.
    const float4* X4 = (const float4*)(X + (size_t)r0 * 256);
    #pragma unroll
    for (int k = 0; k < 8; ++k) {
        int idx = t + 256 * k;          // 0..2047
        int row = idx >> 6;             // 64 float4 per row
        int c4  = idx & 63;
        float4 v = X4[idx];
        short4 s;
        s.x = f2bf(v.x); s.y = f2bf(v.y); s.z = f2bf(v.z); s.w = f2bf(v.w);
        *(short4*)&xlds[row * LSTR + c4 * 4] = s;
    }
    __syncthreads();

    const int lane = t & 63;
    const int wave = t >> 6;            // 4 waves, wave w -> out cols [w*64, w*64+64)
    const int q    = lane >> 4;         // k-group (0..3)
    const int m    = lane & 15;         // A-row / B-col index
    const int o0   = wave * 64;

    floatx4 acc[2][4] = {};             // [row-tile][n-tile]

    #pragma unroll
    for (int it = 0; it < 8; ++it) {
        const int f0 = it * 32 + q * 8;
        // A fragments for the two 16-row tiles: A[m][k], k = q*8 + e
        short8 a0 = *(const short8*)&xlds[m * LSTR + f0];
        short8 a1 = *(const short8*)&xlds[(16 + m) * LSTR + f0];
        #pragma unroll
        for (int nt = 0; nt < 4; ++nt) {
            // B fragment: B[k][n] = W[o0+nt*16+m][f0+k], fp32 -> bf16 in-register
            const float* wp = W + (size_t)(o0 + nt * 16 + m) * 256 + f0;
            float4 w0 = *(const float4*)wp;
            float4 w1 = *(const float4*)(wp + 4);
            short8 b;
            b[0] = f2bf(w0.x); b[1] = f2bf(w0.y); b[2] = f2bf(w0.z); b[3] = f2bf(w0.w);
            b[4] = f2bf(w1.x); b[5] = f2bf(w1.y); b[6] = f2bf(w1.z); b[7] = f2bf(w1.w);
            acc[0][nt] = __builtin_amdgcn_mfma_f32_16x16x32_bf16(a0, b, acc[0][nt], 0, 0, 0);
            acc[1][nt] = __builtin_amdgcn_mfma_f32_16x16x32_bf16(a1, b, acc[1][nt], 0, 0, 0);
        }
    }

    // C/D layout: col = lane&15, row = (lane>>4)*4 + reg  (verified m89/m91)
    #pragma unroll
    for (int rt = 0; rt < 2; ++rt) {
        #pragma unroll
        for (int nt = 0; nt < 4; ++nt) {
            #pragma unroll
            for (int reg = 0; reg < 4; ++reg) {
                int row = r0 + rt * 16 + q * 4 + reg;
                int col = o0 + nt * 16 + m;
                out[(size_t)row * 256 + col] = acc[rt][nt][reg];
            }
        }
    }
}

extern "C" void kernel_launch(void* const* d_in, const int* in_sizes, int n_in,
                              void* d_out, int out_size, void* d_ws, size_t ws_size,
                              hipStream_t stream) {
    const float* x = (const float*)d_in[0];   // [4][2048][256] fp32
    // d_in[1] = adj (dead), d_in[3] = a_w (dead)
    const float* W = (const float*)d_in[2];   // [256][256] fp32
    float* out     = (float*)d_out;           // [4][2048][256] fp32

    gat_gemm<<<256, 256, 0, stream>>>(x, W, out);
}